// Round 1
// baseline (199.393 us; speedup 1.0000x reference)
//
#include <hip/hip_runtime.h>

#define B_ROWS 4096
#define T_LEN  2048
#define CT     128                 // timesteps per staged chunk
#define NCHUNK (T_LEN / CT)        // 16 (even)

// ---- 16-lane all-reduce via DPP butterfly (pure VALU, no LDS) ----
template<int CTRL>
__device__ __forceinline__ float dpp_add(float x) {
  int y = __builtin_amdgcn_update_dpp(0, __builtin_bit_cast(int, x),
                                      CTRL, 0xf, 0xf, true);
  return x + __builtin_bit_cast(float, y);
}

__device__ __forceinline__ float allreduce16(float x) {
  x = dpp_add<0xB1>(x);    // quad_perm [1,0,3,2] : xor 1
  x = dpp_add<0x4E>(x);    // quad_perm [2,3,0,1] : xor 2
  x = dpp_add<0x141>(x);   // row_half_mirror     : xor 4 (within 8)
  x = dpp_add<0x140>(x);   // row_mirror          : xor 8 (within 16)
  return x;                // every lane of the 16-group holds the sum
}

// ---- stage 4 rows x CT steps x (eps,hs) into LDS via global_load_lds ----
// dst is wave-uniform base; HW writes lane*16B linearly => each call covers
// exactly one row's 1 KiB chunk (64 lanes x 16 B). Row pad (+2 float2) keeps
// 16B alignment and de-conflicts banks between the 4 groups on ds_read.
__device__ __forceinline__ void stage4(const float* __restrict__ inp,
                                       int row0, int t0,
                                       float2 (*buf)[CT + 2], int lane) {
#pragma unroll
  for (int r = 0; r < 4; ++r) {
    const float* src = inp + ((size_t)(row0 + r) * (2 * T_LEN)
                              + (size_t)t0 * 2 + lane * 4);
    __builtin_amdgcn_global_load_lds(
        (const __attribute__((address_space(1))) void*)src,
        (__attribute__((address_space(3))) void*)&buf[r][0],
        16, 0, 0);
  }
}

__device__ __forceinline__ void compute_chunk(const float2 (*buf)[CT + 2],
                                              int grp, float& gamma,
                                              float w0n, float w1n, float bnn,
                                              float c0, float c1,
                                              float* __restrict__ outp,
                                              bool store_lane) {
#pragma unroll 8
  for (int tt = 0; tt < CT; ++tt) {
    float2 eh = buf[grp][tt];                 // ds_read_b64, 16-lane broadcast
    float z  = fmaf(gamma, w1n, fmaf(eh.x, w0n, bnn));  // z = -log2e * z1
    float e  = __builtin_amdgcn_exp2f(z);               // exp(-z1)
    float rr = __builtin_amdgcn_rcpf(1.0f + e);         // sigmoid(z1)
    float s1 = allreduce16(rr * c1);          // sum_j sig_j*w2_j*W1[1,j]*0.1
    gamma = fmaf(-eh.y, s1, gamma);           // gamma -= hs*inv_eta*de_dx1
    float s0 = allreduce16(rr * c0);          // sum_j sig_j*w2_j*W1[0,j]
    if (store_lane) outp[tt] = s0;
  }
}

__global__ __launch_bounds__(64) void gsm_scan_kernel(
    const float* __restrict__ inp, const float* __restrict__ W1f,
    const float* __restrict__ b1f, const float* __restrict__ W2f,
    float* __restrict__ out) {
  // Two DISTINCT shared arrays (not one [2][...]) so the compiler's alias
  // analysis can keep prefetch (global_load_lds) and compute decoupled.
  __shared__ float2 lds0[4][CT + 2];
  __shared__ float2 lds1[4][CT + 2];

  const int lane = threadIdx.x;     // 0..63
  const int grp  = lane >> 4;       // row within wave, 0..3
  const int j    = lane & 15;       // hidden unit
  const int row0 = blockIdx.x << 2;
  const int row  = row0 + grp;

  const float LOG2E = 1.4426950408889634f;
  const float w0n = -LOG2E * W1f[j];
  const float w1n = -LOG2E * W1f[16 + j];
  const float bnn = -LOG2E * b1f[j];
  const float w2j = W2f[j];
  const float c0  = w2j * W1f[j];
  const float c1  = w2j * W1f[16 + j] * 0.1f;   // fold inv_eta = 1/10

  const bool store_lane = (j == 0);
  float gamma = 0.0f;
  float* outrow = out + (size_t)row * T_LEN;

  stage4(inp, row0, 0, lds0, lane);             // prologue: chunk 0

  for (int c = 0; c < NCHUNK; c += 2) {
    stage4(inp, row0, (c + 1) * CT, lds1, lane);        // prefetch c+1
    asm volatile("s_waitcnt vmcnt(4)" ::: "memory");    // chunk c ready
    compute_chunk(lds0, grp, gamma, w0n, w1n, bnn, c0, c1,
                  outrow + c * CT, store_lane);
    if (c + 2 < NCHUNK) stage4(inp, row0, (c + 2) * CT, lds0, lane);
    asm volatile("s_waitcnt vmcnt(4)" ::: "memory");    // chunk c+1 ready
    compute_chunk(lds1, grp, gamma, w0n, w1n, bnn, c0, c1,
                  outrow + (c + 1) * CT, store_lane);
  }
}

extern "C" void kernel_launch(void* const* d_in, const int* in_sizes, int n_in,
                              void* d_out, int out_size, void* d_ws,
                              size_t ws_size, hipStream_t stream) {
  const float* inp = (const float*)d_in[0];   // (B, T, 2) f32
  const float* W1  = (const float*)d_in[1];   // (2, 16)
  const float* b1  = (const float*)d_in[2];   // (16,)
  const float* W2  = (const float*)d_in[3];   // (16, 1)
  // d_in[4] = b2 : unused by the reference computation
  float* out = (float*)d_out;                 // (B, T) f32

  dim3 grid(B_ROWS / 4);   // 1024 blocks, 1 wave each (4 rows/wave)
  dim3 block(64);
  hipLaunchKernelGGL(gsm_scan_kernel, grid, block, 0, stream,
                     inp, W1, b1, W2, out);
}

// Round 2
// 146.386 us; speedup vs baseline: 1.3621x; 1.3621x over previous
//
#include <hip/hip_runtime.h>

#define B_ROWS 4096
#define T_LEN  2048
#define TB     16                 // timesteps per register block
#define NBLK   (T_LEN / TB)       // 128 (even)

// ---- 16-lane all-reduce via DPP butterfly (pure VALU, no LDS) ----
template<int CTRL>
__device__ __forceinline__ float dpp_add(float x) {
  int y = __builtin_amdgcn_update_dpp(0, __builtin_bit_cast(int, x),
                                      CTRL, 0xf, 0xf, true);
  return x + __builtin_bit_cast(float, y);
}

__device__ __forceinline__ float allreduce16(float x) {
  x = dpp_add<0xB1>(x);    // quad_perm [1,0,3,2] : xor 1
  x = dpp_add<0x4E>(x);    // quad_perm [2,3,0,1] : xor 2
  x = dpp_add<0x141>(x);   // row_half_mirror     : xor 4
  x = dpp_add<0x140>(x);   // row_mirror          : xor 8
  return x;                // all 16 lanes of the group hold the sum
}

// One register block: 16 timesteps of (eps,hs) = 8 float4 = 32 VGPRs.
struct Blk { float4 q[8]; };

__device__ __forceinline__ void load_blk(const float4* __restrict__ src,
                                         Blk& b) {
#pragma unroll
  for (int i = 0; i < 8; ++i) b.q[i] = src[i];   // global_load_dwordx4 x8
}

__device__ __forceinline__ void compute_blk(const Blk& b, float& gamma,
                                            float w0n, float w1n, float bnn,
                                            float c0, float c1, int j,
                                            float* __restrict__ outp) {
  // gamma-independent precompute for all 16 steps (off the serial chain)
  float pre[TB], hs[TB];
#pragma unroll
  for (int i = 0; i < 8; ++i) {
    pre[2 * i]     = fmaf(b.q[i].x, w0n, bnn);
    hs[2 * i]      = b.q[i].y;
    pre[2 * i + 1] = fmaf(b.q[i].z, w0n, bnn);
    hs[2 * i + 1]  = b.q[i].w;
  }
  float keep = 0.0f;
#pragma unroll
  for (int t = 0; t < TB; ++t) {
    float z  = fmaf(gamma, w1n, pre[t]);          // z = -log2e * z1
    float e  = __builtin_amdgcn_exp2f(z);         // exp(-z1)
    float r  = __builtin_amdgcn_rcpf(1.0f + e);   // sigmoid(z1)
    float s1 = allreduce16(r * c1);               // on the gamma chain
    gamma    = fmaf(-hs[t], s1, gamma);
    float s0 = allreduce16(r * c0);               // off-chain (output only)
    keep     = (j == t) ? s0 : keep;              // branchless latch
  }
  outp[j] = keep;   // one coalesced 4B store per lane per 16 steps
}

__global__ __launch_bounds__(64) void gsm_scan_kernel(
    const float* __restrict__ inp, const float* __restrict__ W1f,
    const float* __restrict__ b1f, const float* __restrict__ W2f,
    float* __restrict__ out) {
  const int lane = threadIdx.x;     // 0..63
  const int grp  = lane >> 4;       // row within wave, 0..3
  const int j    = lane & 15;       // hidden unit
  const int row  = (blockIdx.x << 2) + grp;

  const float LOG2E = 1.4426950408889634f;
  const float w0n = -LOG2E * W1f[j];
  const float w1n = -LOG2E * W1f[16 + j];
  const float bnn = -LOG2E * b1f[j];
  const float w2j = W2f[j];
  const float c0  = w2j * W1f[j];
  const float c1  = w2j * W1f[16 + j] * 0.1f;   // fold inv_eta = 1/10

  // Each 16-lane group broadcast-reads its own row directly from global.
  const float4* src = (const float4*)(inp + (size_t)row * (2 * T_LEN));
  float* outrow = out + (size_t)row * T_LEN;

  float gamma = 0.0f;
  Blk A, Bb;
  load_blk(src, A);                 // prologue: block 0

#pragma unroll 1
  for (int b = 0; b < NBLK; b += 2) {
    load_blk(src + (size_t)(b + 1) * 8, Bb);                 // prefetch b+1
    compute_blk(A, gamma, w0n, w1n, bnn, c0, c1, j, outrow + b * TB);
    if (b + 2 < NBLK) load_blk(src + (size_t)(b + 2) * 8, A); // prefetch b+2
    compute_blk(Bb, gamma, w0n, w1n, bnn, c0, c1, j, outrow + (b + 1) * TB);
  }
}

extern "C" void kernel_launch(void* const* d_in, const int* in_sizes, int n_in,
                              void* d_out, int out_size, void* d_ws,
                              size_t ws_size, hipStream_t stream) {
  const float* inp = (const float*)d_in[0];   // (B, T, 2) f32
  const float* W1  = (const float*)d_in[1];   // (2, 16)
  const float* b1  = (const float*)d_in[2];   // (16,)
  const float* W2  = (const float*)d_in[3];   // (16, 1)
  // d_in[4] = b2 : unused by the reference computation
  float* out = (float*)d_out;                 // (B, T) f32

  dim3 grid(B_ROWS / 4);   // 1024 waves = 1 per SIMD across 256 CUs
  dim3 block(64);
  hipLaunchKernelGGL(gsm_scan_kernel, grid, block, 0, stream,
                     inp, W1, b1, W2, out);
}

// Round 4
// 137.240 us; speedup vs baseline: 1.4529x; 1.0666x over previous
//
#include <hip/hip_runtime.h>

#define B_ROWS 4096
#define T_LEN  2048
#define TB     16                 // timesteps per register block
#define NBLK   (T_LEN / TB)       // 128 (even)

// ---- DPP helpers via builtins (compiler inserts required hazard nops;
// GCNDPPCombine fuses mov_dpp+add into v_add_f32_dpp where legal) ----
template<int CTRL>
__device__ __forceinline__ float dpp_add(float x) {
  int y = __builtin_amdgcn_update_dpp(0, __builtin_bit_cast(int, x),
                                      CTRL, 0xf, 0xf, true);
  return x + __builtin_bit_cast(float, y);
}

// Butterfly over each 16-lane row: every lane ends with its row's sum.
__device__ __forceinline__ float allreduce16(float x) {
  x = dpp_add<0xB1>(x);    // quad_perm [1,0,3,2] : xor 1
  x = dpp_add<0x4E>(x);    // quad_perm [2,3,0,1] : xor 2
  x = dpp_add<0x141>(x);   // row_half_mirror     : xor 4
  x = dpp_add<0x140>(x);   // row_mirror          : xor 8
  return x;
}

// row_bcast15 (ctrl 0x142), row_mask 0xA: lanes 16-31 get lane 15's value,
// lanes 48-63 get lane 47's value; rows 0 and 2 keep the old value.
__device__ __forceinline__ float bcast_low16(float g) {
  int gi = __builtin_bit_cast(int, g);
  int y  = __builtin_amdgcn_update_dpp(gi, gi, 0x142, 0xA, 0xF, false);
  return __builtin_bit_cast(float, y);
}

// One register block: 16 timesteps of (eps,hs) = 8 float4 = 32 VGPRs.
struct Blk { float4 q[8]; };

__device__ __forceinline__ void load_blk(const float4* __restrict__ src,
                                         Blk& b) {
#pragma unroll
  for (int i = 0; i < 8; ++i) b.q[i] = src[i];   // broadcast within 32 lanes
}

__device__ __forceinline__ void compute_blk(const Blk& b, float& gamma,
                                            float w0n, float w1n, float bnn,
                                            float invc, int j, bool out_half,
                                            float* __restrict__ outp) {
  // gamma-independent precompute for all 16 steps (off the serial chain)
  float pre[TB], hsn[TB];
#pragma unroll
  for (int i = 0; i < 8; ++i) {
    pre[2 * i]     = fmaf(b.q[i].x, w0n, bnn);
    hsn[2 * i]     = -b.q[i].y;
    pre[2 * i + 1] = fmaf(b.q[i].z, w0n, bnn);
    hsn[2 * i + 1] = -b.q[i].w;
  }
  float keep = 0.0f;
#pragma unroll
  for (int t = 0; t < TB; ++t) {
    // serial chain: fma -> exp2 -> fma -> rcp -> 4 dpp-adds -> fma -> bcast
    float z = fmaf(gamma, w1n, pre[t]);          // z = -log2e * z1
    float e = __builtin_amdgcn_exp2f(z);         // exp(-z1)
    float d = fmaf(e, invc, invc);               // (1+e)/c
    float v = __builtin_amdgcn_rcpf(d);          // c * sigmoid(z1)
    float s = allreduce16(v);    // lanes 0-15: s1 ; lanes 16-31: s0
    gamma   = fmaf(hsn[t], s, gamma);            // garbage in upper half...
    gamma   = bcast_low16(gamma);                // ...repaired from lane 15
    keep    = (j == t) ? s : keep;               // upper half latches s0_t
  }
  if (out_half) outp[j] = keep;  // 16 consecutive floats per row per block
}

__global__ __launch_bounds__(64) void gsm_scan_kernel(
    const float* __restrict__ inp, const float* __restrict__ W1f,
    const float* __restrict__ b1f, const float* __restrict__ W2f,
    float* __restrict__ out) {
  const int lane = threadIdx.x;       // 0..63
  const int rid  = lane >> 5;         // row within wave (2 rows/wave)
  const int half = (lane >> 4) & 1;   // 0: sigma*c1 path, 1: sigma*c0 path
  const int j    = lane & 15;         // hidden unit
  const int row  = (blockIdx.x << 1) + rid;

  const float LOG2E = 1.4426950408889634f;
  const float w0n = -LOG2E * W1f[j];
  const float w1n = -LOG2E * W1f[16 + j];
  const float bnn = -LOG2E * b1f[j];
  const float w2j = W2f[j];
  const float c   = half ? (w2j * W1f[j])               // c0 (output path)
                         : (w2j * W1f[16 + j] * 0.1f);  // c1 (gamma path)
  const float invc = 1.0f / c;

  const float4* src = (const float4*)(inp + (size_t)row * (2 * T_LEN));
  float* outrow = out + (size_t)row * T_LEN;
  const bool out_half = (half == 1);

  float gamma = 0.0f;
  Blk A, Bb;
  load_blk(src, A);                 // prologue: block 0

#pragma unroll 1
  for (int b = 0; b < NBLK; b += 2) {
    load_blk(src + (size_t)(b + 1) * 8, Bb);                  // prefetch b+1
    compute_blk(A, gamma, w0n, w1n, bnn, invc, j, out_half, outrow + b * TB);
    if (b + 2 < NBLK) load_blk(src + (size_t)(b + 2) * 8, A); // prefetch b+2
    compute_blk(Bb, gamma, w0n, w1n, bnn, invc, j, out_half,
                outrow + (b + 1) * TB);
  }
}

extern "C" void kernel_launch(void* const* d_in, const int* in_sizes, int n_in,
                              void* d_out, int out_size, void* d_ws,
                              size_t ws_size, hipStream_t stream) {
  const float* inp = (const float*)d_in[0];   // (B, T, 2) f32
  const float* W1  = (const float*)d_in[1];   // (2, 16)
  const float* b1  = (const float*)d_in[2];   // (16,)
  const float* W2  = (const float*)d_in[3];   // (16, 1)
  // d_in[4] = b2 : unused by the reference computation
  float* out = (float*)d_out;                 // (B, T) f32

  dim3 grid(B_ROWS / 2);   // 2048 waves = 2 per SIMD (TLP hides chain stalls)
  dim3 block(64);
  hipLaunchKernelGGL(gsm_scan_kernel, grid, block, 0, stream,
                     inp, W1, b1, W2, out);
}

// Round 7
// 119.560 us; speedup vs baseline: 1.6677x; 1.1479x over previous
//
#include <hip/hip_runtime.h>

#define B_ROWS 4096
#define T_LEN  2048
#define TB     16                 // timesteps per register block
#define NBLK   (T_LEN / TB)       // 128 (even)

// ---- DPP butterfly via builtins ONLY (R2/R4-proven; asm DPP abandoned
// after two deterministic failures with identical wrong output). ----
template<int CTRL>
__device__ __forceinline__ float dpp_add(float x) {
  int y = __builtin_amdgcn_update_dpp(0, __builtin_bit_cast(int, x),
                                      CTRL, 0xf, 0xf, true);
  return x + __builtin_bit_cast(float, y);
}

// Butterfly over each 16-lane row: every lane ends with its row's sum.
__device__ __forceinline__ float allreduce16(float x) {
  x = dpp_add<0xB1>(x);    // quad_perm [1,0,3,2] : xor 1
  x = dpp_add<0x4E>(x);    // quad_perm [2,3,0,1] : xor 2
  x = dpp_add<0x141>(x);   // row_half_mirror     : xor 4
  x = dpp_add<0x140>(x);   // row_mirror          : xor 8
  return x;
}

// One register block: 16 timesteps of (eps,hs) = 8 float4 = 32 VGPRs.
struct Blk { float4 q[8]; };

__device__ __forceinline__ void load_blk(const float4* __restrict__ src,
                                         Blk& b) {
#pragma unroll
  for (int i = 0; i < 8; ++i) b.q[i] = src[i];   // broadcast within 16 lanes
}

struct Pre { float dpre[TB - 1]; float hw[TB]; float pre15; };

__device__ __forceinline__ void extract(const Blk& b, float w0n, float bnn,
                                        float w1n, Pre& p) {
  float pre[TB];
#pragma unroll
  for (int i = 0; i < 8; ++i) {
    pre[2 * i]       = fmaf(b.q[i].x, w0n, bnn);
    p.hw[2 * i]      = b.q[i].y * w1n;
    pre[2 * i + 1]   = fmaf(b.q[i].z, w0n, bnn);
    p.hw[2 * i + 1]  = b.q[i].w * w1n;
  }
#pragma unroll
  for (int t = 0; t < TB - 1; ++t) p.dpre[t] = pre[t + 1] - pre[t];
  p.pre15 = pre[TB - 1];
}

// 16 steps in z-form: z = gamma*w1n + pre (everything pre-scaled by -log2e).
// CHAIN (per step): exp2 -> fma -> rcp -> 4 dpp-adds -> fma.  No bcast: all
// 16 lanes run the c1 path, so every lane holds a correct s1 and correct z.
// OFF-CHAIN: P = z + dpre; v0 = ratio*r (c0 path); s0 butterfly; latch.
__device__ __forceinline__ void compute16(const Pre& p, float nextq0x,
                                          bool peek, float& z, float invc1,
                                          float ratio, float w0n, float bnn,
                                          int j, float* __restrict__ outp) {
  float keep = 0.0f;
#pragma unroll
  for (int t = 0; t < TB; ++t) {
    float e  = __builtin_amdgcn_exp2f(z);          // exp(-z1)
    float d  = fmaf(e, invc1, invc1);              // (1+e)/c1
    float r  = __builtin_amdgcn_rcpf(d);           // c1 * sigmoid(z1)
    float s1 = allreduce16(r);                     // chain: gamma-path sum
    // off-chain work (fills trans/butterfly stall slots):
    float dpre_t = (t < TB - 1)
                     ? p.dpre[t]
                     : (peek ? (fmaf(nextq0x, w0n, bnn) - p.pre15) : 0.0f);
    float P  = z + dpre_t;
    float v0 = r * ratio;                          // c0 * sigmoid (exact-ish)
    float s0 = allreduce16(v0);                    // output-path sum
    z    = fmaf(-p.hw[t], s1, P);                  // z' correct in ALL lanes
    keep = (j == t) ? s0 : keep;                   // branchless latch
  }
  outp[j] = keep;   // 16 consecutive floats per row per block
}

__global__ __launch_bounds__(64) void gsm_scan_kernel(
    const float* __restrict__ inp, const float* __restrict__ W1f,
    const float* __restrict__ b1f, const float* __restrict__ W2f,
    float* __restrict__ out) {
  const int lane = threadIdx.x;       // 0..63
  const int grp  = lane >> 4;         // row within wave, 0..3
  const int j    = lane & 15;         // hidden unit
  const int row  = (blockIdx.x << 2) + grp;

  const float LOG2E = 1.4426950408889634f;
  const float w0n = -LOG2E * W1f[j];
  const float w1n = -LOG2E * W1f[16 + j];
  const float bnn = -LOG2E * b1f[j];
  const float w2j = W2f[j];
  const float c0  = w2j * W1f[j];              // output-path coefficient
  const float c1  = w2j * W1f[16 + j] * 0.1f;  // gamma-path coeff (inv_eta)
  const float invc1 = 1.0f / c1;
  const float ratio = c0 * invc1;              // v0 = ratio * (c1*sig)

  const float4* src = (const float4*)(inp + (size_t)row * (2 * T_LEN));
  float* outrow = out + (size_t)row * T_LEN;

  Blk A, Bb;
  Pre p;
  load_blk(src, A);                  // block 0
  load_blk(src + 8, Bb);             // block 1
  float z = fmaf(A.q[0].x, w0n, bnn);  // z0 = pre0 (gamma0 = 0)

#pragma unroll 1
  for (int b = 0; b < NBLK; b += 2) {
    // ---- phase 1: block b from A; prefetch b+2 into A's (now dead) regs
    extract(A, w0n, bnn, w1n, p);
    if (b + 2 < NBLK) load_blk(src + (size_t)(b + 2) * 8, A);
    compute16(p, Bb.q[0].x, true, z, invc1, ratio, w0n, bnn, j,
              outrow + b * TB);
    // ---- phase 2: block b+1 from Bb; prefetch b+3 into Bb's regs
    extract(Bb, w0n, bnn, w1n, p);
    if (b + 3 < NBLK) load_blk(src + (size_t)(b + 3) * 8, Bb);
    compute16(p, A.q[0].x, (b + 2 < NBLK), z, invc1, ratio, w0n, bnn, j,
              outrow + (b + 1) * TB);
  }
}

extern "C" void kernel_launch(void* const* d_in, const int* in_sizes, int n_in,
                              void* d_out, int out_size, void* d_ws,
                              size_t ws_size, hipStream_t stream) {
  const float* inp = (const float*)d_in[0];   // (B, T, 2) f32
  const float* W1  = (const float*)d_in[1];   // (2, 16)
  const float* b1  = (const float*)d_in[2];   // (16,)
  const float* W2  = (const float*)d_in[3];   // (16, 1)
  // d_in[4] = b2 : unused by the reference computation
  float* out = (float*)d_out;                 // (B, T) f32

  dim3 grid(B_ROWS / 4);   // 1024 waves = 1 per SIMD; issue << chain, so
  dim3 block(64);          // TLP is not needed — chain length is the wall
  hipLaunchKernelGGL(gsm_scan_kernel, grid, block, 0, stream,
                     inp, W1, b1, W2, out);
}